// Round 1
// 214.364 us; speedup vs baseline: 1.0724x; 1.0724x over previous
//
#include <hip/hip_runtime.h>
#include <stdint.h>

// SVDQuant forward on MI355X:
//   y = Q4(x*smooth) @ Q4(Wres)^T + (x*smooth) @ lora_down @ lora_up^T + bias
// R5 structure (3 kernels):
//   K0 ldt_kernel: ldT[32][2048] = bf16(lora_down^T)  (makes prep Phase B loads
//      16B-vector instead of 256 scalar L2 loads per lane)
//   K1 prep_kernel (grid 2560):
//     blocks [0,512):   16 x-rows each. Phase A: coalesced fakequant(x*smooth)
//                       -> Xcat[:,0:2048] + bf16 x_s in LDS. Phase B: rank-32 MFMA
//                       t = x_s @ lora_down (B-frags = short8 loads from ldT)
//                       -> Xcat[:,2048:2080].
//     blocks [512,2560): 1 w-row each: Wcat[:,0:2048]=fakequant(Wres),
//                       [2048:2080)=bf16(lora_up).
//   K2 gemm_kernel: out = Xcat @ Wcat^T + bias, K=2080.
//     256x256 tile, BK=32, 512 thr (8 waves, wave-tile 128x64), 3-buffer LDS ring,
//     depth-2 prefetch with counted s_waitcnt vmcnt(4) (loads stay in flight across
//     the single per-K-step s_barrier), setprio around MFMA cluster, 2-way-max
//     chunk swizzle (pre-swizzled source + swizzled ds_read), XCD-chunked blockIdx.

typedef __attribute__((ext_vector_type(8))) short short8;
typedef __attribute__((ext_vector_type(8))) unsigned short ushort8;
typedef __attribute__((ext_vector_type(4))) unsigned short ushort4v;
typedef __attribute__((ext_vector_type(4))) float floatx4;

#define M_TOK 8192
#define K_IN  2048
#define N_OUT 2048
#define RANK  32
#define KC    2080      // 2048 quant + 32 lowrank = 65 * 32 (no pad)
#define NKT   65        // K-tiles of 32
#define XS_STRIDE 2056  // LDS x_s row stride (shorts): +8 -> 4-bank row rotation

// round-to-nearest-even f32 -> bf16 (finite inputs only)
__device__ __forceinline__ unsigned short f2bf(float f) {
  unsigned int u = __float_as_uint(f);
  u += 0x7fff + ((u >> 16) & 1);
  return (unsigned short)(u >> 16);
}

// fakequant 8 values held by this lane; group of 64 = 8 consecutive lanes
__device__ __forceinline__ void quant8(const float* v, unsigned short* q) {
  float amax = 0.f;
#pragma unroll
  for (int i = 0; i < 8; ++i) amax = fmaxf(amax, fabsf(v[i]));
  amax = fmaxf(amax, __shfl_xor(amax, 1, 64));
  amax = fmaxf(amax, __shfl_xor(amax, 2, 64));
  amax = fmaxf(amax, __shfl_xor(amax, 4, 64));
  float scale = fmaxf(amax / 7.0f, 1e-8f);
#pragma unroll
  for (int i = 0; i < 8; ++i) {
    float qq = rintf(v[i] / scale);   // IEEE div + RNE == jnp.round(g/scale)
    qq = fminf(fmaxf(qq, -7.f), 7.f);
    q[i] = f2bf(qq * scale);
  }
}

// ---------------- K0: ldT = bf16(lora_down^T), [32][2048] -------------------
__global__ __launch_bounds__(256) void ldt_kernel(const float* __restrict__ ld,
                                                  unsigned short* __restrict__ ldT) {
  int t = threadIdx.x, b = blockIdx.x;        // 32 blocks x 256 threads
  int r = t & 31, kk = b * 64 + (t >> 5);
#pragma unroll
  for (int i = 0; i < 8; ++i)
    ldT[r * 2048 + kk + i * 8] = f2bf(ld[(size_t)(kk + i * 8) * RANK + r]);
}

// ---------------- K1: fused prep --------------------------------------------
__global__ __launch_bounds__(256) void prep_kernel(const float* __restrict__ x,
                                                   const float* __restrict__ smooth,
                                                   const float* __restrict__ wgt,
                                                   const unsigned short* __restrict__ ldT,
                                                   const float* __restrict__ lup,
                                                   unsigned short* __restrict__ Xcat,
                                                   unsigned short* __restrict__ Wcat) {
  __shared__ unsigned short xs[16 * XS_STRIDE];  // 64.25 KiB bf16 x_s
  __shared__ float red[4][16][32];               // 8 KiB
  int tid = threadIdx.x;

  if (blockIdx.x >= 512) {
    // ---- W path: one row of Wres per block ----
    int row = blockIdx.x - 512;
    const float4* wr = (const float4*)(wgt + (size_t)row * K_IN);
    float4 a0 = wr[tid * 2], a1 = wr[tid * 2 + 1];
    float v[8] = {a0.x, a0.y, a0.z, a0.w, a1.x, a1.y, a1.z, a1.w};
    ushort8 q;
    quant8(v, (unsigned short*)&q);
    *(ushort8*)(Wcat + (size_t)row * KC + tid * 8) = q;
    if (tid < 32) Wcat[(size_t)row * KC + 2048 + tid] = f2bf(lup[row * RANK + tid]);
    return;
  }

  // ---- X path: 16 rows per block ----
  int rowbase = blockIdx.x * 16;
  int w = tid >> 6, lane = tid & 63, quad = lane >> 4, l16 = lane & 15;

  // Phase A: coalesced quantize, one row per pass (256 thr x 8 elems = 2048)
  const float4* sr = (const float4*)smooth;
  float4 s0 = sr[tid * 2], s1 = sr[tid * 2 + 1];
#pragma unroll 2
  for (int r = 0; r < 16; ++r) {
    const float4* xr = (const float4*)(x + (size_t)(rowbase + r) * K_IN);
    float4 a0 = xr[tid * 2], a1 = xr[tid * 2 + 1];
    float v[8] = {a0.x * s0.x, a0.y * s0.y, a0.z * s0.z, a0.w * s0.w,
                  a1.x * s1.x, a1.y * s1.y, a1.z * s1.z, a1.w * s1.w};
    ushort8 q;
    quant8(v, (unsigned short*)&q);
    *(ushort8*)(Xcat + (size_t)(rowbase + r) * KC + tid * 8) = q;
    ushort8 sb;
#pragma unroll
    for (int t = 0; t < 8; ++t) sb[t] = f2bf(v[t]);
    *(ushort8*)(xs + r * XS_STRIDE + tid * 8) = sb;
  }
  __syncthreads();

  // Phase B: t = x_s @ lora_down. wave w covers k in [w*512, w*512+512).
  floatx4 acc[2];
  acc[0] = (floatx4)0.f;
  acc[1] = (floatx4)0.f;
  int kbase = w * 512;
#pragma unroll 2
  for (int it = 0; it < 16; ++it) {
    int k = kbase + it * 32 + quad * 8;
    short8 af = *(const short8*)(xs + l16 * XS_STRIDE + k);
    // B-frag: B[k=quad*8+j][n=l16 (+16)] = ldT[n][k..k+7] -- one 16B load each
    short8 b0 = *(const short8*)(ldT + (size_t)l16 * 2048 + k);
    short8 b1 = *(const short8*)(ldT + (size_t)(16 + l16) * 2048 + k);
    acc[0] = __builtin_amdgcn_mfma_f32_16x16x32_bf16(af, b0, acc[0], 0, 0, 0);
    acc[1] = __builtin_amdgcn_mfma_f32_16x16x32_bf16(af, b1, acc[1], 0, 0, 0);
  }
  // C layout: row = quad*4 + r, col = l16 (+16 for acc[1])
#pragma unroll
  for (int nt = 0; nt < 2; ++nt)
#pragma unroll
    for (int r = 0; r < 4; ++r)
      red[w][quad * 4 + r][nt * 16 + l16] = acc[nt][r];
  __syncthreads();
  if (tid < 128) {
    int rl = tid >> 3, seg = tid & 7;  // row 0..15, col segment of 4
    ushort4v o;
#pragma unroll
    for (int j = 0; j < 4; ++j) {
      int c = seg * 4 + j;
      float s = red[0][rl][c] + red[1][rl][c] + red[2][rl][c] + red[3][rl][c];
      o[j] = f2bf(s);
    }
    *(ushort4v*)(Xcat + (size_t)(rowbase + rl) * KC + 2048 + seg * 4) = o;
  }
}

// ---------------- K2: main GEMM: out = Xcat @ Wcat^T + bias ----------------
__device__ __forceinline__ void gld_lds16(const unsigned short* g, unsigned short* l) {
  __builtin_amdgcn_global_load_lds(
      (const __attribute__((address_space(1))) unsigned int*)g,
      (__attribute__((address_space(3))) unsigned int*)l, 16, 0, 0);
}

__global__ __launch_bounds__(512) void gemm_kernel(const unsigned short* __restrict__ Xcat,
                                                   const unsigned short* __restrict__ Wcat,
                                                   const float* __restrict__ bias,
                                                   float* __restrict__ out) {
  // 3 K-tile buffers x (A 256x32 + B 256x32) bf16 = 96 KiB
  __shared__ unsigned short smem[49152];
  int tid = threadIdx.x;
  int w = tid >> 6, lane = tid & 63, quad = lane >> 4, l16 = lane & 15;
  int wm = w >> 2, wn = w & 3;  // 2 M-waves x 4 N-waves; wave tile 128x64

  // Bijective XCD chunking: grid 256 = 8 XCDs x 32; each XCD gets a contiguous
  // chunk = 4 M-panels x 8 N-panels -> A/B panel slabs stay L2-resident.
  int bid = blockIdx.x;
  int wg = (bid & 7) * 32 + (bid >> 3);
  int bM = (wg >> 3) * 256;
  int bN = (wg & 7) * 256;

  // Staging: A tile = 256 rows x 4 chunks(16B). thread covers chunks {tid, tid+512}
  // -> row = 128*rd + tid/4, lin chunk = tid&3. Source chunk pre-swizzled with
  // (row>>1)&3 == (tid>>3)&3 (same for both rd) so swizzled ds_reads see linear data.
  int rowA = tid >> 2;
  int csrc = (tid & 3) ^ ((tid >> 3) & 3);
  const unsigned short* Ag = Xcat + (size_t)(bM + rowA) * KC + csrc * 8;
  const unsigned short* Bg = Wcat + (size_t)(bN + rowA) * KC + csrc * 8;
  int ldsA = w * 512;         // wave-uniform LDS dest (shorts), + cbuf + rd*4096
  int ldsB = 8192 + w * 512;

#define STAGE(k0, cbuf)                                                      \
  do {                                                                       \
    gld_lds16(Ag + (k0),            smem + (cbuf) + ldsA);                   \
    gld_lds16(Ag + 128 * KC + (k0), smem + (cbuf) + 4096 + ldsA);            \
    gld_lds16(Bg + (k0),            smem + (cbuf) + ldsB);                   \
    gld_lds16(Bg + 128 * KC + (k0), smem + (cbuf) + 4096 + ldsB);            \
  } while (0)

  // fragment read offsets (shorts): row*32 + swizzled chunk. (r>>1)&3 == (l16>>1)&3
  int cx = (quad ^ ((l16 >> 1) & 3)) * 8;
  int aoff = (wm * 128 + l16) * 32 + cx;          // + mt*512 + cbuf
  int boff = 8192 + (wn * 64 + l16) * 32 + cx;    // + nt*512 + cbuf

  floatx4 acc[8][4];
#pragma unroll
  for (int mt = 0; mt < 8; ++mt)
#pragma unroll
    for (int nt = 0; nt < 4; ++nt) acc[mt][nt] = (floatx4)0.f;

  int c0 = 0, c1 = 16384, c2 = 32768;  // buffer ring (shorts)

  // prologue: tiles 0,1 in flight; certify tile 0 landed (vmcnt counts in-order)
  STAGE(0, c0);
  STAGE(32, c1);
  asm volatile("s_waitcnt vmcnt(4)" ::: "memory");
  __builtin_amdgcn_s_barrier();

  for (int t = 0; t < NKT; ++t) {
    if (t + 2 < NKT) STAGE((t + 2) * 32, c2);  // depth-2 prefetch into dead buffer

    short8 a[8], b[4];
#pragma unroll
    for (int mt = 0; mt < 8; ++mt) a[mt] = *(const short8*)(smem + c0 + aoff + mt * 512);
#pragma unroll
    for (int nt = 0; nt < 4; ++nt) b[nt] = *(const short8*)(smem + c0 + boff + nt * 512);

    __builtin_amdgcn_s_setprio(1);
#pragma unroll
    for (int mt = 0; mt < 8; ++mt)
#pragma unroll
      for (int nt = 0; nt < 4; ++nt)
        acc[mt][nt] = __builtin_amdgcn_mfma_f32_16x16x32_bf16(a[mt], b[nt],
                                                              acc[mt][nt], 0, 0, 0);
    __builtin_amdgcn_s_setprio(0);

    // certify tile t+1 landed; leave tile t+2's 4 loads in flight across barrier
    if (t < NKT - 2)
      asm volatile("s_waitcnt vmcnt(4)" ::: "memory");
    else
      asm volatile("s_waitcnt vmcnt(0)" ::: "memory");
    __builtin_amdgcn_s_barrier();
    int tmp = c0; c0 = c1; c1 = c2; c2 = tmp;
  }
#undef STAGE

  // epilogue: + bias, store fp32
#pragma unroll
  for (int nt = 0; nt < 4; ++nt) {
    int col = bN + wn * 64 + nt * 16 + l16;
    float bv = bias[col];
#pragma unroll
    for (int mt = 0; mt < 8; ++mt) {
      int row = bM + wm * 128 + mt * 16 + quad * 4;
#pragma unroll
      for (int r2 = 0; r2 < 4; ++r2)
        out[(size_t)(row + r2) * N_OUT + col] = acc[mt][nt][r2] + bv;
    }
  }
}

extern "C" void kernel_launch(void* const* d_in, const int* in_sizes, int n_in,
                              void* d_out, int out_size, void* d_ws, size_t ws_size,
                              hipStream_t stream) {
  const float* x      = (const float*)d_in[0];
  const float* wgt    = (const float*)d_in[1];
  const float* ld     = (const float*)d_in[2];
  const float* lup    = (const float*)d_in[3];
  const float* smooth = (const float*)d_in[4];
  const float* bias   = (const float*)d_in[5];
  float* out = (float*)d_out;

  unsigned short* Xcat = (unsigned short*)d_ws;                 // 8192*2080*2 = 34.1 MB
  unsigned short* Wcat = Xcat + (size_t)M_TOK * KC;             //  8.5 MB
  unsigned short* ldT  = Wcat + (size_t)N_OUT * KC;             //  128 KB

  hipLaunchKernelGGL(ldt_kernel, dim3(K_IN / 64), dim3(256), 0, stream, ld, ldT);
  hipLaunchKernelGGL(prep_kernel, dim3(512 + N_OUT), dim3(256), 0, stream,
                     x, smooth, wgt, ldT, lup, Xcat, Wcat);
  hipLaunchKernelGGL(gemm_kernel, dim3((M_TOK / 256) * (N_OUT / 256)), dim3(512), 0, stream,
                     Xcat, Wcat, bias, out);
}